// Round 4
// baseline (307.961 us; speedup 1.0000x reference)
//
#include <hip/hip_runtime.h>
#include <cmath>

#define D_MODEL 1024
#define QLEN    1024
#define NHEAD   16
#define DHEAD   64
#define BSZ     4

typedef __bf16 bf16x8 __attribute__((ext_vector_type(8)));
typedef float  f32x4  __attribute__((ext_vector_type(4)));

static __device__ __forceinline__ __bf16 f2bf(float x) { return (__bf16)x; }

#define MFMA16(a, b, c) __builtin_amdgcn_mfma_f32_16x16x32_bf16((a), (b), (c), 0, 0, 0)

// ---------------------------------------------------------------------------
// fp32 -> bf16 flat convert (weights). n8 = elements/8.
// ---------------------------------------------------------------------------
__global__ __launch_bounds__(256)
void cvt_kernel(const float* __restrict__ s, __bf16* __restrict__ d, int n8)
{
    const int i = blockIdx.x * 256 + threadIdx.x;
    if (i >= n8) return;
    const float4 a = *(const float4*)(s + (size_t)i * 8);
    const float4 b = *(const float4*)(s + (size_t)i * 8 + 4);
    bf16x8 o;
    o[0] = f2bf(a.x); o[1] = f2bf(a.y); o[2] = f2bf(a.z); o[3] = f2bf(a.w);
    o[4] = f2bf(b.x); o[5] = f2bf(b.y); o[6] = f2bf(b.z); o[7] = f2bf(b.w);
    *(bf16x8*)(d + (size_t)i * 8) = o;
}

// ---------------------------------------------------------------------------
// Transpose + convert: src fp32 [1024 c][1024 l] -> dst bf16 [1024 l][1024 c].
// Slabs 0-3: z batches; slab 4: pos_emb.
// ---------------------------------------------------------------------------
__global__ __launch_bounds__(256)
void transpose_cvt_kernel(const float* __restrict__ z, const float* __restrict__ pos,
                          __bf16* __restrict__ zT, __bf16* __restrict__ posT)
{
    const int slab = blockIdx.z;
    const float* src = (slab < 4) ? z + (size_t)slab * 1048576 : pos;
    __bf16*      dst = (slab < 4) ? zT + (size_t)slab * 1048576 : posT;
    const int c0 = blockIdx.y * 64, l0 = blockIdx.x * 64;

    __shared__ float tile[64][68];
    const int t = threadIdx.x;
    {
        const int c = t >> 4, l4 = (t & 15) * 4;
#pragma unroll
        for (int r = 0; r < 4; ++r) {
            const int cc = c + r * 16;
            const float4 v = *(const float4*)(src + (size_t)(c0 + cc) * 1024 + l0 + l4);
            tile[cc][l4 + 0] = v.x; tile[cc][l4 + 1] = v.y;
            tile[cc][l4 + 2] = v.z; tile[cc][l4 + 3] = v.w;
        }
    }
    __syncthreads();
    {
        const int l = t >> 2, cb = (t & 3) * 16;
#pragma unroll
        for (int h = 0; h < 2; ++h) {
            bf16x8 o;
#pragma unroll
            for (int e = 0; e < 8; ++e) o[e] = f2bf(tile[cb + h * 8 + e][l]);
            *(bf16x8*)(dst + (size_t)(l0 + l) * 1024 + c0 + cb + h * 8) = o;
        }
    }
}

// ---------------------------------------------------------------------------
// bf16 MFMA GEMM: C[b][m][n] = sum_k A[m][k] * Bm[b][n][k] + epilogue.
//   MODE 0: natural bf16 out, +u          (V section of QKV)
//   MODE 1: TRANSPOSED bf16 out (Cw=2048), +u   (Q,K sections -> whqkT[l][c])
//   MODE 2: TRANSPOSED bf16 out (Cw=1024)       (rk -> rkT[r][c])
//   MODE 3: natural fp32 out, +bias[m]+res      (out proj)
// 128x128 tile, BK=64, 4 waves (2x2), 4x4 16x16x32 frags per wave.
// ---------------------------------------------------------------------------
template<int MODE>
__global__ __launch_bounds__(256)
void bgemm_kernel(const __bf16* __restrict__ A, const __bf16* __restrict__ Bm,
                  const float* __restrict__ add32, size_t add_bstride,
                  const float* __restrict__ bias, void* __restrict__ Cout,
                  int M, int K, int N)
{
    const int b  = blockIdx.z;
    const int m0 = blockIdx.y * 128;
    const int n0 = blockIdx.x * 128;
    const __bf16* Bb = Bm + (size_t)b * N * K;

    __shared__ __align__(16) __bf16 smem[2 * 128 * 72];
    __bf16 (*As)[72] = (__bf16(*)[72])smem;
    __bf16 (*Bs)[72] = (__bf16(*)[72])(smem + 128 * 72);

    const int t  = threadIdx.x;
    const int w  = t >> 6, l = t & 63;
    const int lr = l & 15, lg = l >> 4;
    const int wr = w >> 1, wc = w & 1;

    f32x4 acc[4][4];
#pragma unroll
    for (int mi = 0; mi < 4; ++mi)
#pragma unroll
        for (int ni = 0; ni < 4; ++ni) acc[mi][ni] = (f32x4){0.f, 0.f, 0.f, 0.f};

    const int srow = t >> 1, sh = (t & 1) * 32;

    for (int k0 = 0; k0 < K; k0 += 64) {
        __syncthreads();
        const __bf16* ag = A  + (size_t)(m0 + srow) * K + k0 + sh;
        const __bf16* bg = Bb + (size_t)(n0 + srow) * K + k0 + sh;
#pragma unroll
        for (int j = 0; j < 4; ++j) {
            *(bf16x8*)&As[srow][sh + j * 8] = *(const bf16x8*)(ag + j * 8);
            *(bf16x8*)&Bs[srow][sh + j * 8] = *(const bf16x8*)(bg + j * 8);
        }
        __syncthreads();

#pragma unroll
        for (int kk = 0; kk < 2; ++kk) {
            bf16x8 af[4], bfr[4];
#pragma unroll
            for (int mi = 0; mi < 4; ++mi)
                af[mi] = *(const bf16x8*)&As[wr * 64 + mi * 16 + lr][kk * 32 + lg * 8];
#pragma unroll
            for (int ni = 0; ni < 4; ++ni)
                bfr[ni] = *(const bf16x8*)&Bs[wc * 64 + ni * 16 + lr][kk * 32 + lg * 8];
#pragma unroll
            for (int mi = 0; mi < 4; ++mi)
#pragma unroll
                for (int ni = 0; ni < 4; ++ni)
                    acc[mi][ni] = MFMA16(af[mi], bfr[ni], acc[mi][ni]);
        }
    }

    if constexpr (MODE == 0 || MODE == 3) {
        // natural-layout epilogue
        const size_t cb = (size_t)b * M * N;
#pragma unroll
        for (int mi = 0; mi < 4; ++mi)
#pragma unroll
        for (int q = 0; q < 4; ++q) {
            const int m = m0 + wr * 64 + mi * 16 + lg * 4 + q;
#pragma unroll
            for (int ni = 0; ni < 4; ++ni) {
                const int n = n0 + wc * 64 + ni * 16 + lr;
                float v = acc[mi][ni][q];
                const size_t aoff = (size_t)b * add_bstride + (size_t)m * N + n;
                if (MODE == 0) {
                    v += add32[aoff];
                    ((__bf16*)Cout)[cb + (size_t)m * N + n] = f2bf(v);
                } else {
                    v += bias[m] + add32[aoff];
                    ((float*)Cout)[cb + (size_t)m * N + n] = v;
                }
            }
        }
    } else {
        // transposed epilogue: bounce through LDS, coalesced [n][m] store
        __syncthreads();
        __bf16 (*T)[136] = (__bf16(*)[136])smem;
#pragma unroll
        for (int mi = 0; mi < 4; ++mi)
#pragma unroll
        for (int ni = 0; ni < 4; ++ni)
#pragma unroll
        for (int q = 0; q < 4; ++q) {
            float v = acc[mi][ni][q];
            if (MODE == 1) {
                const int m = m0 + wr * 64 + mi * 16 + lg * 4 + q;
                const int n = n0 + wc * 64 + ni * 16 + lr;
                v += add32[(size_t)b * add_bstride + (size_t)m * N + n];
            }
            T[wc * 64 + ni * 16 + lr][wr * 64 + mi * 16 + lg * 4 + q] = f2bf(v);
        }
        __syncthreads();
        const int Cw = (MODE == 1) ? 2048 : 1024;
        __bf16* co = (__bf16*)Cout + (size_t)b * 1024 * Cw;
#pragma unroll
        for (int it2 = 0; it2 < 8; ++it2) {
            const int row = it2 * 16 + w * 4 + (l >> 4);
            const int col = (l & 15) * 8;
            *(bf16x8*)(co + (size_t)(n0 + row) * Cw + m0 + col) = *(const bf16x8*)&T[row][col];
        }
    }
}

// ---------------------------------------------------------------------------
// MFMA bf16 fused rel-attention. All staging linear (pre-transposed inputs);
// rel-shift gather via cross-lane shuffle (no LDS spill).
// Grid: (16 i-tiles, 16 heads, 4 batch), 256 threads = 4 waves.
// ---------------------------------------------------------------------------
__global__ __launch_bounds__(256)
void attn_mfma_kernel(const __bf16* __restrict__ whqkT, // [b][l][2048] (Q|K)
                      const __bf16* __restrict__ wh_v,  // [b][1024][1024]
                      const __bf16* __restrict__ rkT,   // [1024 r][1024 c]
                      const float* __restrict__ rwb,    // (16,64)
                      const float* __restrict__ rrb,    // (16,64)
                      __bf16* __restrict__ avT)         // [b][l][1024]
{
    const int it = 15 - blockIdx.x;   // longest blocks first
    const int i0 = it * 64;
    const int n  = blockIdx.y;
    const int b  = blockIdx.z;

    __shared__ __align__(16) __bf16 kt[64][72];    // [j][d]
    __shared__ __align__(16) __bf16 rkt[128][72];  // [rr][d]
    __shared__ __align__(16) __bf16 vs[64][72];    // [d][j]
    __shared__ __align__(16) __bf16 ps[64][72];    // [i][j] probs / [i][d] out

    const int t  = threadIdx.x;
    const int w  = t >> 6;
    const int l  = t & 63;
    const int lr = l & 15;
    const int lg = l >> 4;

    // ---- Q fragments: qa = q + rwb, qb = q + rrb (direct vector loads) ----
    bf16x8 qa[2], qb[2];
    {
        const int iq = i0 + w * 16 + lr;
        const __bf16* qp = whqkT + ((size_t)b * 1024 + iq) * 2048 + n * 64;
#pragma unroll
        for (int h = 0; h < 2; ++h) {
            const bf16x8 q8 = *(const bf16x8*)(qp + h * 32 + lg * 8);
#pragma unroll
            for (int e = 0; e < 8; ++e) {
                const float qv = (float)q8[e];
                qa[h][e] = f2bf(qv + rwb[n * 64 + h * 32 + lg * 8 + e]);
                qb[h][e] = f2bf(qv + rrb[n * 64 + h * 32 + lg * 8 + e]);
            }
        }
    }

    f32x4 acc_o[4];
#pragma unroll
    for (int i = 0; i < 4; ++i) acc_o[i] = (f32x4){0.f, 0.f, 0.f, 0.f};
    float m_r[4] = {-INFINITY, -INFINITY, -INFINITY, -INFINITY};
    float l_r[4] = {0.f, 0.f, 0.f, 0.f};

    const int njt = it + 1;
    const int rt0 = 3 - w;   // wave's first BD r-tile

    for (int jt = 0; jt < njt; ++jt) {
        const int j0 = jt * 64;
        __syncthreads();

        // ---- stage K, V: linear vector copies ----
#pragma unroll
        for (int u2 = 0; u2 < 2; ++u2) {
            const int c = t + u2 * 256;
            const int r8 = c >> 3, dc = (c & 7) * 8;
            *(bf16x8*)&kt[r8][dc] =
                *(const bf16x8*)(whqkT + ((size_t)b * 1024 + j0 + r8) * 2048 + 1024 + n * 64 + dc);
            *(bf16x8*)&vs[r8][dc] =
                *(const bf16x8*)(wh_v + ((size_t)b * 1024 + n * 64 + r8) * 1024 + j0 + dc);
        }
        // ---- stage RK window (clamp top) ----
        const int rbase = j0 - i0 + 960;
#pragma unroll
        for (int u4 = 0; u4 < 4; ++u4) {
            const int c = t + u4 * 256;
            const int rr = c >> 3, dc = (c & 7) * 8;
            bf16x8 v8;
            if (rbase + rr < 1024)
                v8 = *(const bf16x8*)(rkT + (size_t)(rbase + rr) * 1024 + n * 64 + dc);
            else {
#pragma unroll
                for (int e = 0; e < 8; ++e) v8[e] = f2bf(0.f);
            }
            *(bf16x8*)&rkt[rr][dc] = v8;
        }
        __syncthreads();

        // ---- AC MFMAs ----
        f32x4 ac[4];
#pragma unroll
        for (int nt = 0; nt < 4; ++nt) {
            ac[nt] = (f32x4){0.f, 0.f, 0.f, 0.f};
#pragma unroll
            for (int h = 0; h < 2; ++h) {
                const bf16x8 bk = *(const bf16x8*)&kt[nt * 16 + lr][h * 32 + lg * 8];
                ac[nt] = MFMA16(qa[h], bk, ac[nt]);
            }
        }
        // ---- BDraw MFMAs (5 r-tiles for this wave) ----
        f32x4 bda[5];
#pragma unroll
        for (int nt = 0; nt < 5; ++nt) {
            bda[nt] = (f32x4){0.f, 0.f, 0.f, 0.f};
#pragma unroll
            for (int h = 0; h < 2; ++h) {
                const bf16x8 br = *(const bf16x8*)&rkt[(rt0 + nt) * 16 + lr][h * 32 + lg * 8];
                bda[nt] = MFMA16(qb[h], br, bda[nt]);
            }
        }

        // ---- rel-shift gather via shuffle + mask + online softmax ----
        // BD[il][nt*16+lr] = bda[nt + carry][lane (l&48)|((lr+sh)&15)],
        //   sh = 15-(lg*4+q), carry = (lr+sh)>=16.
        float pm[4][4], tmax[4], tsum[4], cc[4];
#pragma unroll
        for (int q = 0; q < 4; ++q) {
            const int shq  = 15 - lg * 4 - q;
            const int srcl = (l & 48) | ((lr + shq) & 15);
            float sb[5];
#pragma unroll
            for (int a = 0; a < 5; ++a) sb[a] = __shfl(bda[a][q], srcl, 64);
            const bool lo = (lr + shq) < 16;
            const int il = w * 16 + lg * 4 + q;
            const int gi = i0 + il;
            float mx = -INFINITY;
#pragma unroll
            for (int nt = 0; nt < 4; ++nt) {
                const int gj = j0 + nt * 16 + lr;
                float s = (ac[nt][q] + (lo ? sb[nt] : sb[nt + 1])) * 0.125f;
                const bool valid = (gj <= gi) && (gj >= gi - 999);
                s = valid ? s : -INFINITY;
                pm[q][nt] = s;
                mx = fmaxf(mx, s);
            }
            tmax[q] = mx;
        }
#pragma unroll
        for (int msk = 1; msk <= 8; msk <<= 1)
#pragma unroll
            for (int q = 0; q < 4; ++q)
                tmax[q] = fmaxf(tmax[q], __shfl_xor(tmax[q], msk));
#pragma unroll
        for (int q = 0; q < 4; ++q) {
            const float mnew = fmaxf(m_r[q], tmax[q]);
            cc[q] = __expf(m_r[q] - mnew);
            m_r[q] = mnew;
            float ts = 0.f;
#pragma unroll
            for (int nt = 0; nt < 4; ++nt) {
                const float p = __expf(pm[q][nt] - mnew);
                pm[q][nt] = p;
                ts += p;
            }
            tsum[q] = ts;
        }
#pragma unroll
        for (int msk = 1; msk <= 8; msk <<= 1)
#pragma unroll
            for (int q = 0; q < 4; ++q)
                tsum[q] += __shfl_xor(tsum[q], msk);
#pragma unroll
        for (int q = 0; q < 4; ++q)
            l_r[q] = l_r[q] * cc[q] + tsum[q];

        // write P (bf16, wave-private rows)
#pragma unroll
        for (int q = 0; q < 4; ++q)
#pragma unroll
            for (int nt = 0; nt < 4; ++nt)
                ps[w * 16 + lg * 4 + q][nt * 16 + lr] = f2bf(pm[q][nt]);

        // rescale O accumulators
#pragma unroll
        for (int ntd = 0; ntd < 4; ++ntd)
#pragma unroll
            for (int q = 0; q < 4; ++q)
                acc_o[ntd][q] *= cc[q];

        // ---- PV MFMAs ----
#pragma unroll
        for (int h = 0; h < 2; ++h) {
            const bf16x8 ap = *(const bf16x8*)&ps[w * 16 + lr][h * 32 + lg * 8];
#pragma unroll
            for (int ntd = 0; ntd < 4; ++ntd) {
                const bf16x8 bv = *(const bf16x8*)&vs[ntd * 16 + lr][h * 32 + lg * 8];
                acc_o[ntd] = MFMA16(ap, bv, acc_o[ntd]);
            }
        }
    }

    // ---- output: [i][d] bf16 via ps reuse, coalesced avT store ----
    float linv[4];
#pragma unroll
    for (int q = 0; q < 4; ++q) linv[q] = 1.f / l_r[q];

    __syncthreads();
#pragma unroll
    for (int ntd = 0; ntd < 4; ++ntd)
#pragma unroll
        for (int q = 0; q < 4; ++q)
            ps[w * 16 + lg * 4 + q][ntd * 16 + lr] = f2bf(acc_o[ntd][q] * linv[q]);
    __syncthreads();
    {
        const int oi = t >> 2, odc = (t & 3) * 16;
        __bf16* dst = avT + ((size_t)b * 1024 + i0 + oi) * 1024 + n * 64 + odc;
        *(bf16x8*)(dst + 0) = *(const bf16x8*)&ps[oi][odc];
        *(bf16x8*)(dst + 8) = *(const bf16x8*)&ps[oi][odc + 8];
    }
}

// ---------------------------------------------------------------------------
// In-place channel LayerNorm over dim 1 of (B, 1024, 1024).
// ---------------------------------------------------------------------------
__global__ __launch_bounds__(256)
void ln_kernel(float* __restrict__ x)
{
    const int b  = blockIdx.y;
    const int li = threadIdx.x & 63;
    const int cp = threadIdx.x >> 6;
    const int l  = blockIdx.x * 64 + li;
    float* xb = x + (size_t)b * D_MODEL * QLEN;

    float s = 0.f, s2 = 0.f;
    for (int c = cp * 256; c < (cp + 1) * 256; ++c) {
        const float v = xb[(size_t)c * QLEN + l];
        s += v; s2 += v * v;
    }
    __shared__ float sum1[4][64], sum2[4][64], mean[64], rstd[64];
    sum1[cp][li] = s;
    sum2[cp][li] = s2;
    __syncthreads();
    if (threadIdx.x < 64) {
        const int q = threadIdx.x;
        const float a  = sum1[0][q] + sum1[1][q] + sum1[2][q] + sum1[3][q];
        const float a2 = sum2[0][q] + sum2[1][q] + sum2[2][q] + sum2[3][q];
        const float mu  = a * (1.f / 1024.f);
        const float var = a2 * (1.f / 1024.f) - mu * mu;
        mean[q] = mu;
        rstd[q] = rsqrtf(var + 1e-5f);
    }
    __syncthreads();
    const float mu = mean[li];
    const float rs = rstd[li];
    for (int c = cp * 256; c < (cp + 1) * 256; ++c) {
        const size_t idx = (size_t)c * QLEN + l;
        xb[idx] = (xb[idx] - mu) * rs;
    }
}

// ---------------------------------------------------------------------------
extern "C" void kernel_launch(void* const* d_in, const int* in_sizes, int n_in,
                              void* d_out, int out_size, void* d_ws, size_t ws_size,
                              hipStream_t stream)
{
    const float* z     = (const float*)d_in[0];
    const float* pos   = (const float*)d_in[1];
    const float* u     = (const float*)d_in[2];
    const float* qkv_w = (const float*)d_in[3];
    const float* r_w   = (const float*)d_in[4];
    const float* rwb   = (const float*)d_in[5];
    const float* rrb   = (const float*)d_in[6];
    const float* o_w   = (const float*)d_in[7];
    const float* o_b   = (const float*)d_in[8];
    float* out = (float*)d_out;

    char* p = (char*)d_ws;
    __bf16* whqkT = (__bf16*)p;  p += (size_t)4 * 1024 * 2048 * 2;   // 16.8 MB
    __bf16* wh_v  = (__bf16*)p;  p += (size_t)4 * 1024 * 1024 * 2;   //  8.4 MB
    __bf16* rkT   = (__bf16*)p;  p += (size_t)1024 * 1024 * 2;       //  2.1 MB
    __bf16* avT   = (__bf16*)p;  p += (size_t)4 * 1024 * 1024 * 2;   //  8.4 MB
    __bf16* zT    = (__bf16*)p;  p += (size_t)4 * 1024 * 1024 * 2;   //  8.4 MB
    __bf16* posT  = (__bf16*)p;  p += (size_t)1024 * 1024 * 2;       //  2.1 MB
    __bf16* qw_bf = (__bf16*)p;  p += (size_t)3072 * 1024 * 2;       //  6.3 MB
    __bf16* rw_bf = (__bf16*)p;  p += (size_t)1024 * 1024 * 2;       //  2.1 MB
    __bf16* ow_bf = (__bf16*)p;                                      //  2.1 MB

    // prep
    cvt_kernel<<<1536, 256, 0, stream>>>(qkv_w, qw_bf, 3072 * 1024 / 8);
    cvt_kernel<<<512,  256, 0, stream>>>(r_w,   rw_bf, 1024 * 1024 / 8);
    cvt_kernel<<<512,  256, 0, stream>>>(o_w,   ow_bf, 1024 * 1024 / 8);
    transpose_cvt_kernel<<<dim3(16, 16, 5), 256, 0, stream>>>(z, pos, zT, posT);

    // 1a. Q,K sections of w_heads, transposed out: whqkT[b][l][0..2048)
    bgemm_kernel<1><<<dim3(8, 16, 4), 256, 0, stream>>>(
        qw_bf, zT, u, (size_t)3072 * 1024, nullptr, whqkT, 2048, 1024, 1024);
    // 1b. V section, natural out: wh_v[b][c][l]
    bgemm_kernel<0><<<dim3(8, 8, 4), 256, 0, stream>>>(
        qw_bf + (size_t)2048 * 1024, zT, u + (size_t)2048 * 1024,
        (size_t)3072 * 1024, nullptr, wh_v, 1024, 1024, 1024);

    // 2. rk transposed: rkT[r][c]
    bgemm_kernel<2><<<dim3(8, 8, 1), 256, 0, stream>>>(
        rw_bf, posT, nullptr, 0, nullptr, rkT, 1024, 1024, 1024);

    // 3. fused rel-attention -> avT (bf16, [b][l][c])
    attn_mfma_kernel<<<dim3(16, 16, 4), 256, 0, stream>>>(
        whqkT, wh_v, rkT, rwb, rrb, avT);

    // 4. out = o_w @ attn_vec + o_b + z  (fp32, into d_out)
    bgemm_kernel<3><<<dim3(8, 8, 4), 256, 0, stream>>>(
        ow_bf, avT, z, (size_t)1024 * 1024, o_b, out, 1024, 1024, 1024);

    // 5. channel LayerNorm in place
    ln_kernel<<<dim3(16, 4), 256, 0, stream>>>(out);
}